// Round 5
// baseline (267.027 us; speedup 1.0000x reference)
//
#include <hip/hip_runtime.h>

typedef float f32x2 __attribute__((ext_vector_type(2)));

#define PAD 3
#define HH 320
#define WW 1024
#define BB 8
#define PLANE ((size_t)HH * WW)

#define TWO 58                 // output (center) columns per tile (lanes 3..60)
#define NCT 18                 // column tiles: centers 0..1046 cover all valid cols
#define TH 40                  // output rows per block
#define NRT 8                  // 320/40 row tiles
#define RPW 10                 // rows per wave (4 waves x 10)
#define NWAVES 4
#define NTHREADS 256

#define NIN ((HH - 2*PAD) * (WW - 2*PAD))
#define OUT_SCALE (1.0 / (49.0 * (double)BB * (double)HH * (double)WW))
#define C0 ((float)(48.0 * (double)BB * (double)NIN * OUT_SCALE))
#define NEG_SCALE ((float)(-0.1 * OUT_SCALE))

static __device__ __forceinline__ f32x2 mk2(float a, float b){ f32x2 r; r.x=a; r.y=b; return r; }
static __device__ __forceinline__ f32x2 sp2(float a){ f32x2 r; r.x=a; r.y=a; return r; }
static __device__ __forceinline__ f32x2 fma2(f32x2 a, f32x2 b, f32x2 c){
    return __builtin_elementwise_fma(a, b, c);
}
static __device__ __forceinline__ float lane_get(float v, int addr){
    return __int_as_float(__builtin_amdgcn_ds_bpermute(addr, __float_as_int(v)));
}

// Two offsets at once (compiler f32x2 -> v_pk_*; round-1 verified exact).
//   t^2 = s*(s*A - 2*dx*dy), s=rsq(ax*ay), A=dx^2*ay+dy^2*ax, a*=0.81+d*^2
//   w1/(0.1+t1^2)+w2/(0.1+t2^2) = rcp(b1*b2)*(w1*b2+w2*b1); INTERIOR: w==2
template<bool INTERIOR>
static __device__ __forceinline__ void pair2(f32x2 nx, f32x2 ny, f32x2 cx2, f32x2 cy2,
                                             f32x2 w2, float& acc)
{
    f32x2 dx  = nx - cx2;
    f32x2 dy  = ny - cy2;
    f32x2 dx2 = dx * dx;
    f32x2 dy2 = dy * dy;
    f32x2 ax  = dx2 + sp2(0.81f);
    f32x2 ay  = dy2 + sp2(0.81f);
    f32x2 P   = ax * ay;
    f32x2 s; s.x = __builtin_amdgcn_rsqf(P.x); s.y = __builtin_amdgcn_rsqf(P.y);
    f32x2 A   = fma2(dx2, ay, dy2 * ax);
    f32x2 h   = dx * dy;
    f32x2 inner = fma2(s, A, h * sp2(-2.0f));
    f32x2 t2  = s * inner;
    f32x2 den = t2 + sp2(0.1f);
    float ip  = __builtin_amdgcn_rcpf(den.x * den.y);
    float cross;
    if constexpr (INTERIOR) cross = den.x + den.y;
    else                    cross = fmaf(w2.x, den.y, w2.y * den.x);
    acc = fmaf(ip, cross, acc);
}

template<bool INTERIOR>
static __device__ __forceinline__ float strip(
    const float* __restrict__ xb, const float* __restrict__ yb,
    int gi0, int colJ, float colF3,
    int adm3, int adm2, int adm1, int adp1, int adp2, int adp3)
{
    // border-only column flags (round-1 weight machinery, verified exact)
    float cO3 = 0.0f;
    f32x2 cP0 = {}, cP1 = {}, cP2 = {}, cP3 = {};
    if constexpr (!INTERIOR) {
        float cO[7];
        #pragma unroll
        for (int d = 0; d < 7; ++d) {
            int nj = colJ + d - 3;
            cO[d] = (nj >= PAD && nj < WW - PAD) ? 1.0f : 0.0f;
        }
        cP0 = mk2(cO[0], cO[1]);
        cP1 = mk2(cO[2], cO[3]);
        cP2 = mk2(cO[4], cO[5]);
        cP3 = sp2(cO[6]);
        cO3 = cO[3];
    }

    float Lx[3][3], Ly[3][3], s3r[3];   // global-load ring (3 deep, 6 floats/row)
    float wx[4][7], wy[4][7];           // shifted-window ring (4 rows live)

    // issue the 6 raw channel loads for window row r (clamped, masked via s3r)
#define ISSUE(r) { \
    const int ri_ = (r) % 3; \
    const int gr_ = gi0 + (r); \
    const int gc_ = (gr_ < HH) ? gr_ : (HH - 1); \
    const float* bx_ = xb + (size_t)gc_ * WW; \
    const float* by_ = yb + (size_t)gc_ * WW; \
    Lx[ri_][0] = bx_[0]; Lx[ri_][1] = bx_[PLANE]; Lx[ri_][2] = bx_[2*PLANE]; \
    Ly[ri_][0] = by_[0]; Ly[ri_][1] = by_[PLANE]; Ly[ri_][2] = by_[2*PLANE]; \
    s3r[ri_] = (gr_ < HH) ? colF3 : 0.0f; }

    // consume row r: intensities + 12 bpermute lane-shifts into window slot SL
#define PROC(r, SL) { \
    const int ri_ = (r) % 3; \
    const float Ix_ = (Lx[ri_][0] + Lx[ri_][1] + Lx[ri_][2]) * s3r[ri_]; \
    const float Iy_ = (Ly[ri_][0] + Ly[ri_][1] + Ly[ri_][2]) * s3r[ri_]; \
    wx[SL][3] = Ix_;                    wy[SL][3] = Iy_; \
    wx[SL][0] = lane_get(Ix_, adm3);    wy[SL][0] = lane_get(Iy_, adm3); \
    wx[SL][1] = lane_get(Ix_, adm2);    wy[SL][1] = lane_get(Iy_, adm2); \
    wx[SL][2] = lane_get(Ix_, adm1);    wy[SL][2] = lane_get(Iy_, adm1); \
    wx[SL][4] = lane_get(Ix_, adp1);    wy[SL][4] = lane_get(Iy_, adp1); \
    wx[SL][5] = lane_get(Ix_, adp2);    wy[SL][5] = lane_get(Iy_, adp2); \
    wx[SL][6] = lane_get(Ix_, adp3);    wy[SL][6] = lane_get(Iy_, adp3); }

    // software pipeline: prefetch distance 2 rows
    ISSUE(0) ISSUE(1) ISSUE(2)
    PROC(0, 0) ISSUE(3)
    PROC(1, 1) ISSUE(4)
    PROC(2, 2)

    float acc = 0.0f;

    #pragma unroll
    for (int iu = 0; iu < RPW; ++iu) {
        if (iu + 5 <= RPW + 2) ISSUE(iu + 5)      // folds after unroll
        PROC(iu + 3, ((iu + 3) & 3))

        const int gi = gi0 + iu;
        float rin[4] = {};
        f32x2 mc2 = {};
        if constexpr (!INTERIOR) {
            #pragma unroll
            for (int di = 0; di < 4; ++di) {
                int ni = gi + di;
                rin[di] = (ni >= PAD && ni < HH - PAD) ? 1.0f : 0.0f;
            }
            mc2 = sp2(rin[0] * cO3);
        }

        const int s0 = iu & 3, s1 = (iu+1)&3, s2 = (iu+2)&3, s3_ = (iu+3)&3;
        const f32x2 cx2 = sp2(wx[s0][3]);
        const f32x2 cy2 = sp2(wy[s0][3]);

        // di = 0, dj = +1,+2
        pair2<INTERIOR>(mk2(wx[s0][4], wx[s0][5]), mk2(wy[s0][4], wy[s0][5]),
            cx2, cy2, INTERIOR ? sp2(0.0f) : fma2(sp2(rin[0]), cP2, mc2), acc);

        // di = 1..3: dj-pair groups A(-3,-2), B(-1,0), C(+1,+2)
        #pragma unroll
        for (int di = 1; di <= 3; ++di) {
            const int s = (iu + di) & 3;
            const f32x2 rin2 = sp2(rin[di]);
            pair2<INTERIOR>(mk2(wx[s][0], wx[s][1]), mk2(wy[s][0], wy[s][1]),
                cx2, cy2, INTERIOR ? sp2(0.0f) : fma2(rin2, cP0, mc2), acc);
            pair2<INTERIOR>(mk2(wx[s][2], wx[s][3]), mk2(wy[s][2], wy[s][3]),
                cx2, cy2, INTERIOR ? sp2(0.0f) : fma2(rin2, cP1, mc2), acc);
            pair2<INTERIOR>(mk2(wx[s][4], wx[s][5]), mk2(wy[s][4], wy[s][5]),
                cx2, cy2, INTERIOR ? sp2(0.0f) : fma2(rin2, cP2, mc2), acc);
        }

        // leftovers dj = +3, packed across di: (0,1) and (2,3)
        pair2<INTERIOR>(mk2(wx[s0][6], wx[s1][6]), mk2(wy[s0][6], wy[s1][6]),
            cx2, cy2, INTERIOR ? sp2(0.0f) : fma2(mk2(rin[0], rin[1]), cP3, mc2), acc);
        pair2<INTERIOR>(mk2(wx[s2][6], wx[s3_][6]), mk2(wy[s2][6], wy[s3_][6]),
            cx2, cy2, INTERIOR ? sp2(0.0f) : fma2(mk2(rin[2], rin[3]), cP3, mc2), acc);
    }
#undef ISSUE
#undef PROC
    return acc;
}

__global__ __launch_bounds__(NTHREADS, 4) void ternary_loss_kernel(
    const float* __restrict__ x, const float* __restrict__ y,
    float* __restrict__ out)
{
    __shared__ float wave_sums[NWAVES];

    const int t      = blockIdx.x;          // column tile
    const int tile_i = blockIdx.y * TH;
    const int b      = blockIdx.z;
    const int tx  = threadIdx.x;            // 0..63
    const int wv  = threadIdx.y;            // 0..3
    const int tid = wv * 64 + tx;

    // lane's loaded column; tiles overlap by 6 lanes for the shuffle halo
    const int colJ   = t * TWO + tx;
    const int colC   = (colJ < WW) ? colJ : (WW - 1);
    const float colF3 = (colJ < WW) ? (1.0f / 3.0f) : 0.0f;

    const float* xb = x + (size_t)b * 3 * PLANE + colC;
    const float* yb = y + (size_t)b * 3 * PLANE + colC;
    const int gi0 = tile_i + wv * RPW;

    // bpermute byte addresses for lane shifts dj = -3..-1, +1..+3
    const int adm3 = ((tx - 3) & 63) << 2;
    const int adm2 = ((tx - 2) & 63) << 2;
    const int adm1 = ((tx - 1) & 63) << 2;
    const int adp1 = ((tx + 1) & 63) << 2;
    const int adp2 = ((tx + 2) & 63) << 2;
    const int adp3 = ((tx + 3) & 63) << 2;

    // center-enumeration ownership: columns partitioned exactly once across tiles
    const float activeF = ((tx <= 60) && (tx >= 3 || t == 0)) ? 1.0f : 0.0f;

    // block-uniform: every pair touched by active lanes has weight exactly 2
    const bool interior = (t >= 1) && (t <= NCT - 2)
                       && (tile_i >= PAD) && (tile_i + TH - 1 + PAD <= HH - PAD - 1);

    float acc;
    if (interior)
        acc = 2.0f * strip<true >(xb, yb, gi0, colJ, colF3,
                                  adm3, adm2, adm1, adp1, adp2, adp3);
    else
        acc =        strip<false>(xb, yb, gi0, colJ, colF3,
                                  adm3, adm2, adm1, adp1, adp2, adp3);
    acc *= activeF;

    // reduction: wave shuffle -> LDS across 4 waves -> one atomic
    #pragma unroll
    for (int off = 32; off > 0; off >>= 1)
        acc += __shfl_down(acc, off, 64);
    if (tx == 0) wave_sums[wv] = acc;
    __syncthreads();
    if (tid == 0) {
        float total = (wave_sums[0] + wave_sums[1] + wave_sums[2] + wave_sums[3]) * NEG_SCALE;
        if (blockIdx.x == 0 && blockIdx.y == 0 && blockIdx.z == 0)
            total += C0;                    // analytic sum(w)*1 term, added once
        atomicAdd(out, total);
    }
}

extern "C" void kernel_launch(void* const* d_in, const int* in_sizes, int n_in,
                              void* d_out, int out_size, void* d_ws, size_t ws_size,
                              hipStream_t stream) {
    const float* x = (const float*)d_in[0];
    const float* y = (const float*)d_in[1];
    float* out = (float*)d_out;

    hipMemsetAsync(out, 0, sizeof(float), stream);

    dim3 grid(NCT, NRT, BB);   // 18 x 8 x 8 = 1152 blocks
    dim3 block(64, NWAVES, 1);
    ternary_loss_kernel<<<grid, block, 0, stream>>>(x, y, out);
}

// Round 6
// 118.177 us; speedup vs baseline: 2.2596x; 2.2596x over previous
//
#include <hip/hip_runtime.h>

typedef float f32x2 __attribute__((ext_vector_type(2)));
typedef float f32x4 __attribute__((ext_vector_type(4)));

#define PAD 3
#define HH 320
#define WW 1024
#define BB 8
#define TH 32
#define TW 64
#define HALO_H (TH + 2*PAD)   // 38
#define LDS_W  72             // 4 left halo + 64 + 4 right halo, 16B-aligned
#define NF4    (LDS_W/4)      // 18 float4 per staged row
#define NWAVES 4
#define NTHREADS 256
#define ROWS_A 22             // phase-A staged rows (covers output rows 0..15)
#define NPOS_A (ROWS_A * NF4)             // 396
#define NPOS_B ((HALO_H - ROWS_A) * NF4)  // 16*18 = 288

#define NIN ((HH - 2*PAD) * (WW - 2*PAD))
#define OUT_SCALE (1.0 / (49.0 * (double)BB * (double)HH * (double)WW))
#define C0 ((float)(48.0 * (double)BB * (double)NIN * OUT_SCALE))
#define NEG_SCALE ((float)(-0.1 * OUT_SCALE))

// keep a value pinned in a VGPR (defeat LDS-load rematerialization)
#define KEEP(v) asm("" : "+v"(v))

static __device__ __forceinline__ f32x2 mk2(float a, float b){ f32x2 r; r.x=a; r.y=b; return r; }
static __device__ __forceinline__ f32x2 sp2(float a){ f32x2 r; r.x=a; r.y=a; return r; }
static __device__ __forceinline__ f32x2 fma2(f32x2 a, f32x2 b, f32x2 c){
    return __builtin_elementwise_fma(a, b, c);
}

// Two offsets at once (compiler-lowered f32x2; round-1 verified exact, absmax 0).
//   t^2 = s*(s*A - 2*dx*dy), s=rsq(ax*ay), A=dx^2*ay+dy^2*ax, a*=0.81+d*^2
//   w1/(0.1+t1^2)+w2/(0.1+t2^2) = rcp(b1*b2)*(w1*b2+w2*b1);  INTERIOR: w==2
template<bool INTERIOR>
static __device__ __forceinline__ void pair2(f32x2 nx, f32x2 ny, f32x2 cx2, f32x2 cy2,
                                             f32x2 w2, float& acc)
{
    f32x2 dx  = nx - cx2;
    f32x2 dy  = ny - cy2;
    f32x2 dx2 = dx * dx;
    f32x2 dy2 = dy * dy;
    f32x2 ax  = dx2 + sp2(0.81f);
    f32x2 ay  = dy2 + sp2(0.81f);
    f32x2 P   = ax * ay;
    f32x2 s; s.x = __builtin_amdgcn_rsqf(P.x); s.y = __builtin_amdgcn_rsqf(P.y);
    f32x2 A   = fma2(dx2, ay, dy2 * ax);
    f32x2 h   = dx * dy;
    f32x2 inner = fma2(s, A, h * sp2(-2.0f));
    f32x2 t2  = s * inner;
    f32x2 den = t2 + sp2(0.1f);
    float ip  = __builtin_amdgcn_rcpf(den.x * den.y);
    float cross;
    if constexpr (INTERIOR) cross = den.x + den.y;
    else                    cross = fmaf(w2.x, den.y, w2.y * den.x);
    acc = fmaf(ip, cross, acc);
}

// stage one float4 position (absolute staged row r, float4 col c4)
static __device__ __forceinline__ void stage_pos(
    float (&sIx)[HALO_H][LDS_W], float (&sIy)[HALO_H][LDS_W],
    const float* __restrict__ xb, const float* __restrict__ yb,
    int tile_i, int tile_j, int r, int c4)
{
    const size_t PLANE = (size_t)HH * WW;
    int gi  = tile_i - PAD + r;
    int gj0 = tile_j - 4 + 4 * c4;
    f32x4 vx = {0.0f, 0.0f, 0.0f, 0.0f};
    f32x4 vy = {0.0f, 0.0f, 0.0f, 0.0f};
    if ((unsigned)gi < (unsigned)HH && (unsigned)gj0 < (unsigned)WW) {
        const float* px = xb + (size_t)gi * WW + gj0;
        f32x4 a0 = *(const f32x4*)(px);
        f32x4 a1 = *(const f32x4*)(px + PLANE);
        f32x4 a2 = *(const f32x4*)(px + 2 * PLANE);
        vx = (a0 + a1 + a2) * (1.0f / 3.0f);
        const float* py = yb + (size_t)gi * WW + gj0;
        f32x4 b0 = *(const f32x4*)(py);
        f32x4 b1 = *(const f32x4*)(py + PLANE);
        f32x4 b2 = *(const f32x4*)(py + 2 * PLANE);
        vy = (b0 + b1 + b2) * (1.0f / 3.0f);
    }
    *(f32x4*)&sIx[r][4 * c4] = vx;
    *(f32x4*)&sIy[r][4 * c4] = vy;
}

// compute 4 output rows: li0 = li_base + wv*4  (r1 inner body, RPW=4 slice)
template<bool INTERIOR>
static __device__ __forceinline__ float compute_half(
    const float (&sIx)[HALO_H][LDS_W], const float (&sIy)[HALO_H][LDS_W],
    int tile_i, int tile_j, int tx, int wv, int li_base)
{
    float cO3 = 0.0f;
    f32x2 cP0 = {}, cP1 = {}, cP2 = {}, cP3 = {};
    if constexpr (!INTERIOR) {
        float cO[7];
        const int gj = tile_j + tx;
        #pragma unroll
        for (int d = 0; d < 7; ++d) {
            int nj = gj + d - 3;
            cO[d] = (nj >= PAD && nj < WW - PAD) ? 1.0f : 0.0f;
        }
        cP0 = mk2(cO[0], cO[1]);
        cP1 = mk2(cO[2], cO[3]);
        cP2 = mk2(cO[4], cO[5]);
        cP3 = sp2(cO[6]);
        cO3 = cO[3];
    }

    const int li0 = li_base + wv * 4;

    float wx[4][7], wy[4][7];
    #pragma unroll
    for (int r = 0; r < 3; ++r) {
        #pragma unroll
        for (int d = 0; d < 7; ++d) {
            float a = sIx[li0 + 3 + r][tx + 1 + d]; KEEP(a); wx[r][d] = a;
            float c = sIy[li0 + 3 + r][tx + 1 + d]; KEEP(c); wy[r][d] = c;
        }
    }

    float acc = 0.0f;

    #pragma unroll
    for (int iu = 0; iu < 4; ++iu) {
        const int li = li0 + iu;
        const int gi = tile_i + li;
        const int sn = (iu + 3) & 3;
        #pragma unroll
        for (int d = 0; d < 7; ++d) {
            float a = sIx[li + 6][tx + 1 + d]; KEEP(a); wx[sn][d] = a;
            float c = sIy[li + 6][tx + 1 + d]; KEEP(c); wy[sn][d] = c;
        }

        float rin[4] = {};
        f32x2 mc2 = {};
        if constexpr (!INTERIOR) {
            #pragma unroll
            for (int di = 0; di < 4; ++di) {
                int ni = gi + di;
                rin[di] = (ni >= PAD && ni < HH - PAD) ? 1.0f : 0.0f;
            }
            mc2 = sp2(rin[0] * cO3);
        }

        const int s0 = iu & 3, s1 = (iu+1)&3, s2 = (iu+2)&3, s3_ = (iu+3)&3;
        const f32x2 cx2 = sp2(wx[s0][3]);
        const f32x2 cy2 = sp2(wy[s0][3]);

        // di = 0, dj = +1,+2
        pair2<INTERIOR>(mk2(wx[s0][4], wx[s0][5]), mk2(wy[s0][4], wy[s0][5]),
            cx2, cy2, INTERIOR ? sp2(0.0f) : fma2(sp2(rin[0]), cP2, mc2), acc);

        // di = 1..3: dj-pair groups A(-3,-2), B(-1,0), C(+1,+2)
        #pragma unroll
        for (int di = 1; di <= 3; ++di) {
            const int s = (iu + di) & 3;
            const f32x2 rin2 = sp2(rin[di]);
            pair2<INTERIOR>(mk2(wx[s][0], wx[s][1]), mk2(wy[s][0], wy[s][1]),
                cx2, cy2, INTERIOR ? sp2(0.0f) : fma2(rin2, cP0, mc2), acc);
            pair2<INTERIOR>(mk2(wx[s][2], wx[s][3]), mk2(wy[s][2], wy[s][3]),
                cx2, cy2, INTERIOR ? sp2(0.0f) : fma2(rin2, cP1, mc2), acc);
            pair2<INTERIOR>(mk2(wx[s][4], wx[s][5]), mk2(wy[s][4], wy[s][5]),
                cx2, cy2, INTERIOR ? sp2(0.0f) : fma2(rin2, cP2, mc2), acc);
        }

        // leftovers dj = +3, packed across di: (0,1) and (2,3)
        pair2<INTERIOR>(mk2(wx[s0][6], wx[s1][6]), mk2(wy[s0][6], wy[s1][6]),
            cx2, cy2, INTERIOR ? sp2(0.0f) : fma2(mk2(rin[0], rin[1]), cP3, mc2), acc);
        pair2<INTERIOR>(mk2(wx[s2][6], wx[s3_][6]), mk2(wy[s2][6], wy[s3_][6]),
            cx2, cy2, INTERIOR ? sp2(0.0f) : fma2(mk2(rin[2], rin[3]), cP3, mc2), acc);
    }

    return acc;
}

__global__ __launch_bounds__(NTHREADS, 4) void ternary_loss_kernel(
    const float* __restrict__ x, const float* __restrict__ y,
    float* __restrict__ out)
{
    __shared__ __align__(16) float sIx[HALO_H][LDS_W];
    __shared__ __align__(16) float sIy[HALO_H][LDS_W];
    __shared__ float wave_sums[NWAVES];

    const int tile_j = blockIdx.x * TW;
    const int tile_i = blockIdx.y * TH;
    const int b      = blockIdx.z;
    const int tx  = threadIdx.x;            // 0..63
    const int wv  = threadIdx.y;            // 0..3
    const int tid = wv * 64 + tx;

    const size_t PLANE = (size_t)HH * WW;
    const float* xb = x + (size_t)b * 3 * PLANE;
    const float* yb = y + (size_t)b * 3 * PLANE;

    // ---- phase A: stage halo rows [0, 22) -- covers output rows 0..15 ----
    for (int p = tid; p < NPOS_A; p += NTHREADS) {
        int r  = p / NF4;
        int c4 = p - r * NF4;
        stage_pos(sIx, sIy, xb, yb, tile_i, tile_j, r, c4);
    }
    __syncthreads();

    // ---- T14 async-STAGE: ISSUE phase-B loads now (1 position/thread), ----
    // ---- consume them after compute-A so HBM latency hides under VALU  ----
    const int rB  = ROWS_A + tid / NF4;          // staged rows 22..36
    const int cB  = tid - (tid / NF4) * NF4;
    const int giB = tile_i - PAD + rB;
    const int gjB = tile_j - 4 + 4 * cB;
    const bool okB = ((unsigned)giB < (unsigned)HH) && ((unsigned)gjB < (unsigned)WW);
    const size_t offB = okB ? ((size_t)giB * WW + gjB) : 0;   // safe addr if OOB
    const float* pxB = xb + offB;
    const float* pyB = yb + offB;
    f32x4 bx0 = *(const f32x4*)(pxB);
    f32x4 bx1 = *(const f32x4*)(pxB + PLANE);
    f32x4 bx2 = *(const f32x4*)(pxB + 2 * PLANE);
    f32x4 by0 = *(const f32x4*)(pyB);
    f32x4 by1 = *(const f32x4*)(pyB + PLANE);
    f32x4 by2 = *(const f32x4*)(pyB + 2 * PLANE);
    const float mB = okB ? (1.0f / 3.0f) : 0.0f;

    // block-uniform interior test (verified exact r2/r3/r5, absmax 0)
    const bool interior = (tile_i >= PAD) && (tile_i + TH + PAD <= HH - PAD)
                       && (tile_j >= 2*PAD) && (tile_j + TW + PAD <= WW - PAD);

    // ---- compute output rows 0..15 (reads staged rows <= 21 only) ----
    float acc;
    if (interior) acc = compute_half<true >(sIx, sIy, tile_i, tile_j, tx, wv, 0);
    else          acc = compute_half<false>(sIx, sIy, tile_i, tile_j, tx, wv, 0);

    // ---- finish phase-B staging: waitcnt lands here, average, write ----
    {
        f32x4 vx = (bx0 + bx1 + bx2) * mB;
        f32x4 vy = (by0 + by1 + by2) * mB;
        *(f32x4*)&sIx[rB][4 * cB] = vx;
        *(f32x4*)&sIy[rB][4 * cB] = vy;
    }
    // tail: positions 256..287 (rows 36 tail + 37), staged conventionally
    if (tid < NPOS_B - NTHREADS) {
        int q  = NTHREADS + tid;
        int r  = ROWS_A + q / NF4;
        int c4 = q - (q / NF4) * NF4;
        stage_pos(sIx, sIy, xb, yb, tile_i, tile_j, r, c4);
    }
    __syncthreads();

    // ---- compute output rows 16..31 ----
    if (interior) acc += compute_half<true >(sIx, sIy, tile_i, tile_j, tx, wv, 16);
    else          acc += compute_half<false>(sIx, sIy, tile_i, tile_j, tx, wv, 16);

    if (interior) acc *= 2.0f;     // every pair weight == 2 on interior tiles

    // ---- reduction: wave shuffle -> LDS across 4 waves -> one atomic ----
    #pragma unroll
    for (int off = 32; off > 0; off >>= 1)
        acc += __shfl_down(acc, off, 64);
    if (tx == 0) wave_sums[wv] = acc;
    __syncthreads();
    if (tid == 0) {
        float total = (wave_sums[0] + wave_sums[1] + wave_sums[2] + wave_sums[3]) * NEG_SCALE;
        if (blockIdx.x == 0 && blockIdx.y == 0 && blockIdx.z == 0)
            total += C0;                       // analytic  sum(w)*1  term, added once
        atomicAdd(out, total);
    }
}

extern "C" void kernel_launch(void* const* d_in, const int* in_sizes, int n_in,
                              void* d_out, int out_size, void* d_ws, size_t ws_size,
                              hipStream_t stream) {
    const float* x = (const float*)d_in[0];
    const float* y = (const float*)d_in[1];
    float* out = (float*)d_out;

    hipMemsetAsync(out, 0, sizeof(float), stream);

    dim3 grid(WW / TW, HH / TH, BB);   // 16 x 10 x 8 = 1280 blocks
    dim3 block(64, NWAVES, 1);
    ternary_loss_kernel<<<grid, block, 0, stream>>>(x, y, out);
}